// Round 14
// baseline (314.432 us; speedup 1.0000x reference)
//
#include <hip/hip_runtime.h>
#include <math.h>

#define NNODE 20000
#define NEDGE 160000
#define IN_DIMV 256
#define HIDV 128
#define DEGCAP 64
#define BAT 4

typedef __attribute__((ext_vector_type(8))) short bf16x8;
typedef __attribute__((ext_vector_type(4))) float f32x4;
typedef __attribute__((ext_vector_type(2))) float f32x2;

__device__ __forceinline__ float bf2f(unsigned short u) {
    union { unsigned int i; float f; } x; x.i = ((unsigned int)u) << 16; return x.f;
}
__device__ __forceinline__ unsigned short f2bf(float f) {
    union { float f; unsigned int i; } x; x.f = f;
    unsigned int r = x.i + 0x7fffu + ((x.i >> 16) & 1u);
    return (unsigned short)(r >> 16);
}
__device__ __forceinline__ uint2 pack4bf(float a, float b, float c, float d) {
    uint2 r;
    r.x = ((unsigned int)f2bf(a)) | (((unsigned int)f2bf(b)) << 16);
    r.y = ((unsigned int)f2bf(c)) | (((unsigned int)f2bf(d)) << 16);
    return r;
}
__device__ __forceinline__ unsigned int pack4f8(float a, float b, float c, float d) {
    int w = __builtin_amdgcn_cvt_pk_fp8_f32(a, b, 0, false);
    w = __builtin_amdgcn_cvt_pk_fp8_f32(c, d, w, true);
    return (unsigned int)w;
}
__device__ __forceinline__ void unpack8(uint4 p, float* f) {
    f[0] = bf2f((unsigned short)(p.x & 0xffff)); f[1] = bf2f((unsigned short)(p.x >> 16));
    f[2] = bf2f((unsigned short)(p.y & 0xffff)); f[3] = bf2f((unsigned short)(p.y >> 16));
    f[4] = bf2f((unsigned short)(p.z & 0xffff)); f[5] = bf2f((unsigned short)(p.z >> 16));
    f[6] = bf2f((unsigned short)(p.w & 0xffff)); f[7] = bf2f((unsigned short)(p.w >> 16));
}
__device__ __forceinline__ void unpack8f8_w(unsigned int a, unsigned int b, float* f) {
    f32x2 t;
    t = __builtin_amdgcn_cvt_pk_f32_fp8((int)a, false); f[0] = t.x; f[1] = t.y;
    t = __builtin_amdgcn_cvt_pk_f32_fp8((int)a, true);  f[2] = t.x; f[3] = t.y;
    t = __builtin_amdgcn_cvt_pk_f32_fp8((int)b, false); f[4] = t.x; f[5] = t.y;
    t = __builtin_amdgcn_cvt_pk_f32_fp8((int)b, true);  f[6] = t.x; f[7] = t.y;
}
__device__ __forceinline__ void gld_lds16(const unsigned short* g, unsigned short* l) {
    __builtin_amdgcn_global_load_lds((const __attribute__((address_space(1))) void*)g,
                                     (__attribute__((address_space(3))) void*)l, 16, 0, 0);
}
__device__ __forceinline__ void gld_lds16b(const unsigned char* g, unsigned char* l) {
    __builtin_amdgcn_global_load_lds((const __attribute__((address_space(1))) void*)g,
                                     (__attribute__((address_space(3))) void*)l, 16, 0, 0);
}

// ---------------- convert: xbf = bf16(x); weights f32 W[K,N] -> bf16 WT[N,K] arena ----------------
__global__ void convert_kernel(
    const float* __restrict__ x, const float* __restrict__ lin_w,
    const float* __restrict__ qw0, const float* __restrict__ kw0,
    const float* __restrict__ vw0, const float* __restrict__ sw0,
    const float* __restrict__ qw1, const float* __restrict__ kw1,
    const float* __restrict__ vw1, const float* __restrict__ sw1,
    unsigned short* __restrict__ xbf, unsigned short* __restrict__ arena)
{
    int idx = blockIdx.x * 256 + threadIdx.x;
    if (idx < 5120000) { xbf[idx] = f2bf(x[idx]); return; }
    int id2 = idx - 5120000;
    if (id2 >= 458752) return;
    float v;
    if (id2 < 32768) {
        int n = id2 >> 8, k = id2 & 255;
        v = lin_w[k * 128 + n];
    } else {
        int t = id2 - 32768;
        int l = t / 212992, r = t % 212992;
        int n = r >> 7, k = r & 127;
        const float* qw = l ? qw1 : qw0;
        const float* kw = l ? kw1 : kw0;
        const float* vw = l ? vw1 : vw0;
        const float* sw = l ? sw1 : sw0;
        if (n < 1536) {
            const float* w = (n < 512) ? qw : (n < 1024) ? kw : vw;
            v = w[k * 512 + (n & 511)];
        } else {
            v = sw[k * 128 + (n - 1536)];
        }
    }
    arena[id2] = f2bf(v);
}

// ---------------- GEMM0: input projection, K=256, N=128, transposed-acc epilogue ----------------
__global__ __launch_bounds__(256) void mfma_gemm0(
    const unsigned short* __restrict__ A, const unsigned short* __restrict__ WT,
    const float* __restrict__ b0, unsigned short* __restrict__ hbf_out)
{
    __shared__ unsigned short smem[8192];
    unsigned short* As = smem;
    unsigned short* Bs = smem + 4096;
    unsigned short* ot = smem;
    const int K = 256;

    int tid = threadIdx.x;
    int lane = tid & 63;
    int w = tid >> 6;
    int wm = w & 1, wn = w >> 1;
    int bm = blockIdx.x * 128;

    int srow = lane >> 2;
    int scol = (lane & 3) * 8;
    int ar0 = bm + w * 32 + srow;      if (ar0 > NNODE - 1) ar0 = NNODE - 1;
    int ar1 = bm + w * 32 + 16 + srow; if (ar1 > NNODE - 1) ar1 = NNODE - 1;
    int br0 = w * 32 + srow;
    int br1 = w * 32 + 16 + srow;

    f32x4 acc[4][4] = {};
    int arow = wm * 64 + (lane & 15);
    int brow = wn * 64 + (lane & 15);
    int koff = (lane >> 4) * 8;

    for (int k0 = 0; k0 < K; k0 += 32) {
        gld_lds16(A + (size_t)ar0 * K + k0 + scol, As + (w * 32) * 32);
        gld_lds16(A + (size_t)ar1 * K + k0 + scol, As + (w * 32 + 16) * 32);
        gld_lds16(WT + (size_t)br0 * K + k0 + scol, Bs + (w * 32) * 32);
        gld_lds16(WT + (size_t)br1 * K + k0 + scol, Bs + (w * 32 + 16) * 32);
        __syncthreads();
        bf16x8 fa[4], fb[4];
#pragma unroll
        for (int i = 0; i < 4; i++) fa[i] = *(const bf16x8*)&As[(arow + i * 16) * 32 + koff];
#pragma unroll
        for (int i = 0; i < 4; i++) fb[i] = *(const bf16x8*)&Bs[(brow + i * 16) * 32 + koff];
        // transposed: thread holds 4 consecutive cols (reg dim) at row (lane&15)
#pragma unroll
        for (int mi = 0; mi < 4; mi++)
#pragma unroll
            for (int ni = 0; ni < 4; ni++)
                acc[mi][ni] = __builtin_amdgcn_mfma_f32_16x16x32_bf16(fb[ni], fa[mi], acc[mi][ni], 0, 0, 0);
        __syncthreads();
    }

    int quad = lane >> 4, mrow = lane & 15;
#pragma unroll
    for (int hh = 0; hh < 2; hh++) {
        __syncthreads();
        if (wm == hh) {
#pragma unroll
            for (int mi = 0; mi < 4; mi++) {
                int lr = mi * 16 + mrow;   // local row within this 64-half
#pragma unroll
                for (int ni = 0; ni < 4; ni++) {
                    int lc0 = wn * 64 + ni * 16 + quad * 4;
                    float4 bias = *(const float4*)(b0 + lc0);
                    float v0 = fmaxf(acc[mi][ni][0] + bias.x, 0.f);
                    float v1 = fmaxf(acc[mi][ni][1] + bias.y, 0.f);
                    float v2 = fmaxf(acc[mi][ni][2] + bias.z, 0.f);
                    float v3 = fmaxf(acc[mi][ni][3] + bias.w, 0.f);
                    *(uint2*)&ot[lr * 128 + lc0] = pack4bf(v0, v1, v2, v3);
                }
            }
        }
        __syncthreads();
        int r = tid >> 2, ch = tid & 3;
        int row = bm + hh * 64 + r;
        if (row < NNODE) {
            uint4* dp = (uint4*)(hbf_out + (size_t)row * HIDV + ch * 32);
            const uint4* sp = (const uint4*)(ot + r * 128 + ch * 32);
#pragma unroll
            for (int q = 0; q < 4; q++) dp[q] = sp[q];
        }
    }
}

// ---------------- GEMM1: panel-looped, A resident; transposed-acc packed epilogue ----------------
// grid (157, 2): y=0 -> panels 0..6, y=1 -> panels 7..12.
// panel p (bn=p*128): p<4 -> qb bf16; 4<=p<12 -> kv8 fp8; p==12 -> pre16 bf16.
__global__ __launch_bounds__(256) void mfma_gemm1(
    const unsigned short* __restrict__ A, const unsigned short* __restrict__ WT,
    const float* __restrict__ b0, const float* __restrict__ b1,
    const float* __restrict__ b2, const float* __restrict__ b3,
    unsigned short* __restrict__ qb_out, unsigned char* __restrict__ kv8_out,
    unsigned short* __restrict__ pre16_out)
{
    __shared__ unsigned short As[16384];   // 32 KB A tile, 4 k-chunks x [128][32]
    __shared__ unsigned short Ws[16384];   // 32 KB WT panel; reused as epilogue tile
    unsigned short* ot = Ws;
    unsigned char* ot8 = (unsigned char*)Ws;
    const int K = 128;

    int tid = threadIdx.x;
    int lane = tid & 63;
    int w = tid >> 6;
    int wm = w & 1, wn = w >> 1;
    int bm = blockIdx.x * 128;
    int p0 = (blockIdx.y == 0) ? 0 : 7;
    int p1 = (blockIdx.y == 0) ? 7 : 13;

    int srow = lane >> 2;
    int scol = (lane & 3) * 8;
    int sr0 = w * 32 + srow;
    int sr1 = w * 32 + 16 + srow;
    int ar0 = bm + sr0; if (ar0 > NNODE - 1) ar0 = NNODE - 1;
    int ar1 = bm + sr1; if (ar1 > NNODE - 1) ar1 = NNODE - 1;

    // stage A once
#pragma unroll
    for (int c = 0; c < 4; c++) {
        int k0 = c * 32;
        gld_lds16(A + (size_t)ar0 * K + k0 + scol, As + c * 4096 + sr0 * 32);
        gld_lds16(A + (size_t)ar1 * K + k0 + scol, As + c * 4096 + sr1 * 32);
    }

    int arow = wm * 64 + (lane & 15);
    int brow = wn * 64 + (lane & 15);
    int koff = (lane >> 4) * 8;
    int quad = lane >> 4, mrow = lane & 15;

    for (int p = p0; p < p1; p++) {
        int bn = p * 128;
        // stage WT panel
#pragma unroll
        for (int c = 0; c < 4; c++) {
            int k0 = c * 32;
            gld_lds16(WT + (size_t)(bn + sr0) * K + k0 + scol, Ws + c * 4096 + sr0 * 32);
            gld_lds16(WT + (size_t)(bn + sr1) * K + k0 + scol, Ws + c * 4096 + sr1 * 32);
        }
        __syncthreads();   // drains all DMA (incl. A on first iter)

        f32x4 acc[4][4] = {};
#pragma unroll
        for (int c = 0; c < 4; c++) {
            bf16x8 fa[4], fb[4];
#pragma unroll
            for (int i = 0; i < 4; i++) fa[i] = *(const bf16x8*)&As[c * 4096 + (arow + i * 16) * 32 + koff];
#pragma unroll
            for (int i = 0; i < 4; i++) fb[i] = *(const bf16x8*)&Ws[c * 4096 + (brow + i * 16) * 32 + koff];
            // transposed accumulators: 4 consecutive cols per thread
#pragma unroll
            for (int mi = 0; mi < 4; mi++)
#pragma unroll
                for (int ni = 0; ni < 4; ni++)
                    acc[mi][ni] = __builtin_amdgcn_mfma_f32_16x16x32_bf16(fb[ni], fa[mi], acc[mi][ni], 0, 0, 0);
        }
        __syncthreads();   // Ws dead; safe to reuse as ot

        if (p < 4 || p == 12) {
            // bf16 output: full 128x128 tile, packed b64 LDS writes
            const float* bb = (p < 4) ? (b0 + bn) : b3;
#pragma unroll
            for (int mi = 0; mi < 4; mi++) {
                int lr = wm * 64 + mi * 16 + mrow;
#pragma unroll
                for (int ni = 0; ni < 4; ni++) {
                    int lc0 = wn * 64 + ni * 16 + quad * 4;
                    float4 bias = *(const float4*)(bb + lc0);
                    *(uint2*)&ot[lr * 128 + lc0] =
                        pack4bf(acc[mi][ni][0] + bias.x, acc[mi][ni][1] + bias.y,
                                acc[mi][ni][2] + bias.z, acc[mi][ni][3] + bias.w);
                }
            }
            __syncthreads();
            // 2 threads/row, each stores 64 shorts = 128 B = 8 uint4
            int r = tid >> 1, hf = tid & 1;
            int row = bm + r;
            if (row < NNODE) {
                unsigned short* dst = (p < 4) ? (qb_out + (size_t)row * 512 + bn + hf * 64)
                                              : (pre16_out + (size_t)row * HIDV + hf * 64);
                const uint4* sp = (const uint4*)(ot + r * 128 + hf * 64);
                uint4* dp = (uint4*)dst;
#pragma unroll
                for (int q = 0; q < 8; q++) dp[q] = sp[q];
            }
            __syncthreads();
        } else {
            // fp8 output (K/V): full 128x128 byte tile, packed b32 LDS writes
            const float* bb = (bn < 1024) ? (b1 + bn - 512) : (b2 + bn - 1024);
            int coff = bn - 512;
#pragma unroll
            for (int mi = 0; mi < 4; mi++) {
                int lr = wm * 64 + mi * 16 + mrow;
#pragma unroll
                for (int ni = 0; ni < 4; ni++) {
                    int lc0 = wn * 64 + ni * 16 + quad * 4;
                    float4 bias = *(const float4*)(bb + lc0);
                    *(unsigned int*)&ot8[lr * 128 + lc0] =
                        pack4f8(acc[mi][ni][0] + bias.x, acc[mi][ni][1] + bias.y,
                                acc[mi][ni][2] + bias.z, acc[mi][ni][3] + bias.w);
                }
            }
            __syncthreads();
            int r = tid >> 1, hf = tid & 1;
            int row = bm + r;
            if (row < NNODE) {
                uint4* dp = (uint4*)(kv8_out + (size_t)row * 1024 + coff + hf * 64);
                const uint4* sp = (const uint4*)(ot8 + r * 128 + hf * 64);
#pragma unroll
                for (int q = 0; q < 4; q++) dp[q] = sp[q];
            }
            __syncthreads();
        }
    }
}

// ---------------- bucket scatter ----------------
__global__ void scatter_kernel(const int* __restrict__ ei, int* __restrict__ cursor,
                               int* __restrict__ bucket) {
    int e = blockIdx.x * blockDim.x + threadIdx.x;
    if (e < NEDGE) {
        int d = ei[NEDGE + e];
        int slot = atomicAdd(&cursor[d], 1);
        if (slot < DEGCAP) bucket[d * DEGCAP + slot] = ei[e];
    }
}

// ---------------- Fused attention + residual + LayerNorm (unchanged from r13) ----------------
__global__ __launch_bounds__(256) void attn_ln_kernel(
    const unsigned short* __restrict__ qb, const unsigned char* __restrict__ kv8,
    const int* __restrict__ cursor, const int* __restrict__ bucket,
    const unsigned short* __restrict__ pre16, const float* __restrict__ g,
    const float* __restrict__ b,
    unsigned short* __restrict__ hbf /* in: residual; out: LN result */,
    float* __restrict__ extout)
{
    __shared__ __align__(16) unsigned char ring[4][2][BAT * 1024]; // 32 KB
    int lane = threadIdx.x & 63;
    int wid = threadIdx.x >> 6;
    int i = blockIdx.x * 4 + wid;
    int cnt = cursor[i]; if (cnt > DEGCAP) cnt = DEGCAP;
    const int* bk = bucket + i * DEGCAP;

    int hg = lane >> 4;
    int sl = lane & 15;

    float qr[8];
    {
        uint4 p = *(const uint4*)(qb + (size_t)i * 512 + lane * 8);
        unpack8(p, qr);
#pragma unroll
        for (int j = 0; j < 8; j++) qr[j] *= 0.0883883476483184f; // 1/sqrt(128)
    }

    float m = -INFINITY, l = 0.f;
    float acc[8] = {0.f, 0.f, 0.f, 0.f, 0.f, 0.f, 0.f, 0.f};

    if (cnt > 0) {
        int myidx = bk[(lane < cnt) ? lane : 0];

        auto issue = [&](int bb, unsigned char* half) {
#pragma unroll
            for (int t = 0; t < BAT; t++) {
                int j = bb * BAT + t; if (j >= cnt) j = cnt - 1;
                int src = __shfl(myidx, j);
                gld_lds16b(kv8 + (size_t)src * 1024 + lane * 16, half + t * 1024);
            }
        };

        issue(0, ring[wid][0]);
        for (int bb = 0; bb * BAT < cnt; bb++) {
            unsigned char* cur = ring[wid][bb & 1];
            unsigned char* nxt = ring[wid][(bb + 1) & 1];
            bool more = (bb + 1) * BAT < cnt;
            if (more) {
                asm volatile("s_waitcnt lgkmcnt(0)" ::: "memory");
                issue(bb + 1, nxt);
                asm volatile("s_waitcnt vmcnt(4)" ::: "memory");
            } else {
                asm volatile("s_waitcnt vmcnt(0)" ::: "memory");
            }
            int rem = cnt - bb * BAT;

            float d[BAT];
#pragma unroll
            for (int t = 0; t < BAT; t++) d[t] = -3.0e38f;
#pragma unroll
            for (int t = 0; t < BAT; t++) {
                if (t >= rem) break;
                uint2 kk = *(const uint2*)(cur + t * 1024 + hg * 128 + sl * 8);
                float kf[8];
                unpack8f8_w(kk.x, kk.y, kf);
                d[t] = qr[0] * kf[0] + qr[1] * kf[1] + qr[2] * kf[2] + qr[3] * kf[3] +
                       qr[4] * kf[4] + qr[5] * kf[5] + qr[6] * kf[6] + qr[7] * kf[7];
            }
#pragma unroll
            for (int t = 0; t < BAT; t++) { if (t >= rem) break; d[t] += __shfl_xor(d[t], 8); }
#pragma unroll
            for (int t = 0; t < BAT; t++) { if (t >= rem) break; d[t] += __shfl_xor(d[t], 4); }
#pragma unroll
            for (int t = 0; t < BAT; t++) { if (t >= rem) break; d[t] += __shfl_xor(d[t], 2); }
#pragma unroll
            for (int t = 0; t < BAT; t++) { if (t >= rem) break; d[t] += __shfl_xor(d[t], 1); }

            float mq = d[0];
#pragma unroll
            for (int t = 1; t < BAT; t++) mq = fmaxf(mq, d[t]);
            float mn = fmaxf(m, mq);
            float scale = __expf(m - mn);
            float p[BAT];
            float psum = 0.f;
#pragma unroll
            for (int t = 0; t < BAT; t++) { p[t] = __expf(d[t] - mn); psum += p[t]; }
            l = l * scale + psum;
            m = mn;
#pragma unroll
            for (int c = 0; c < 8; c++) acc[c] *= scale;
#pragma unroll
            for (int t = 0; t < BAT; t++) {
                if (t >= rem) break;
                uint2 vv = *(const uint2*)(cur + t * 1024 + 512 + hg * 128 + sl * 8);
                float vf[8];
                unpack8f8_w(vv.x, vv.y, vf);
                float pt = p[t];
#pragma unroll
                for (int c = 0; c < 8; c++) acc[c] += pt * vf[c];
            }
        }
    }

    float linv = 0.25f / (l + 1e-16f);
#pragma unroll
    for (int c = 0; c < 8; c++) acc[c] *= linv;
#pragma unroll
    for (int c = 0; c < 8; c++) {
        acc[c] += __shfl_xor(acc[c], 16);
        acc[c] += __shfl_xor(acc[c], 32);
    }

    size_t base = (size_t)i * HIDV + sl * 8;
    float pv[8], hv[8];
    unpack8(*(const uint4*)(pre16 + base), pv);
    unpack8(*(const uint4*)(hbf + base), hv);
    float vals[8];
#pragma unroll
    for (int c = 0; c < 8; c++) vals[c] = acc[c] + pv[c] + hv[c];

    float s = 0.f;
#pragma unroll
    for (int c = 0; c < 8; c++) s += vals[c];
    s += __shfl_xor(s, 1); s += __shfl_xor(s, 2);
    s += __shfl_xor(s, 4); s += __shfl_xor(s, 8);
    float mu = s * (1.f / 128.f);
    float vs = 0.f;
#pragma unroll
    for (int c = 0; c < 8; c++) { float dx = vals[c] - mu; vs += dx * dx; }
    vs += __shfl_xor(vs, 1); vs += __shfl_xor(vs, 2);
    vs += __shfl_xor(vs, 4); vs += __shfl_xor(vs, 8);
    float rstd = rsqrtf(vs * (1.f / 128.f) + 1e-5f);

    float4 g0 = ((const float4*)(g + sl * 8))[0];
    float4 g1 = ((const float4*)(g + sl * 8))[1];
    float4 bb0 = ((const float4*)(b + sl * 8))[0];
    float4 bb1 = ((const float4*)(b + sl * 8))[1];
    float y[8];
    y[0] = (vals[0] - mu) * rstd * g0.x + bb0.x; y[1] = (vals[1] - mu) * rstd * g0.y + bb0.y;
    y[2] = (vals[2] - mu) * rstd * g0.z + bb0.z; y[3] = (vals[3] - mu) * rstd * g0.w + bb0.w;
    y[4] = (vals[4] - mu) * rstd * g1.x + bb1.x; y[5] = (vals[5] - mu) * rstd * g1.y + bb1.y;
    y[6] = (vals[6] - mu) * rstd * g1.z + bb1.z; y[7] = (vals[7] - mu) * rstd * g1.w + bb1.w;

    if (lane < 16) {
        unsigned short tmp[8] = {f2bf(y[0]), f2bf(y[1]), f2bf(y[2]), f2bf(y[3]),
                                 f2bf(y[4]), f2bf(y[5]), f2bf(y[6]), f2bf(y[7])};
        *(uint4*)(hbf + base) = *(uint4*)tmp;
        if (extout) {
            ((float4*)(extout + base))[0] = make_float4(y[0], y[1], y[2], y[3]);
            ((float4*)(extout + base))[1] = make_float4(y[4], y[5], y[6], y[7]);
        }
    }
}

extern "C" void kernel_launch(void* const* d_in, const int* in_sizes, int n_in,
                              void* d_out, int out_size, void* d_ws, size_t ws_size,
                              hipStream_t stream) {
    const float* x = (const float*)d_in[0];
    const int* ei = (const int*)d_in[1];

    char* ws = (char*)d_ws;
    unsigned short* hbf = (unsigned short*)(ws + 0);          // 5.12 MB
    unsigned short* pre16 = (unsigned short*)(ws + 5120000);  // 5.12 MB
    unsigned short* qb = (unsigned short*)(ws + 10240000);    // 20.48 MB (N x 512 bf16)
    unsigned char* kv8 = (unsigned char*)(ws + 30720000);     // 20.48 MB (N x 1024 fp8)
    unsigned short* xbf = (unsigned short*)(ws + 51200000);   // 10.24 MB
    int* cursor = (int*)(ws + 61440000);                      // 80 KB
    int* bucket = (int*)(ws + 61520000);                      // N x 64 ints = 5.12 MB
    unsigned short* arena = (unsigned short*)(ws + 66640000); // 0.92 MB

    convert_kernel<<<21793, 256, 0, stream>>>(
        x, (const float*)d_in[2],
        (const float*)d_in[4], (const float*)d_in[6], (const float*)d_in[8], (const float*)d_in[10],
        (const float*)d_in[14], (const float*)d_in[16], (const float*)d_in[18], (const float*)d_in[20],
        xbf, arena);

    hipMemsetAsync(cursor, 0, NNODE * sizeof(int), stream);
    scatter_kernel<<<(NEDGE + 255) / 256, 256, 0, stream>>>(ei, cursor, bucket);

    const int GM = (NNODE + 127) / 128; // 157

    mfma_gemm0<<<GM, 256, 0, stream>>>(xbf, arena, (const float*)d_in[3], hbf);

    for (int l = 0; l < 2; l++) {
        int o = 4 + l * 10;
        const unsigned short* WT = arena + 32768 + l * 212992;
        mfma_gemm1<<<dim3(GM, 2), 256, 0, stream>>>(
            hbf, WT,
            (const float*)d_in[o + 1], (const float*)d_in[o + 3],
            (const float*)d_in[o + 5], (const float*)d_in[o + 7],
            qb, kv8, pre16);

        attn_ln_kernel<<<NNODE / 4, 256, 0, stream>>>(
            qb, kv8, cursor, bucket, pre16,
            (const float*)d_in[o + 8], (const float*)d_in[o + 9],
            hbf, (l == 1) ? (float*)d_out : nullptr);
    }
}

// Round 15
// 291.879 us; speedup vs baseline: 1.0773x; 1.0773x over previous
//
#include <hip/hip_runtime.h>
#include <math.h>

#define NNODE 20000
#define NEDGE 160000
#define IN_DIMV 256
#define HIDV 128
#define DEGCAP 64
#define BAT 4

typedef __attribute__((ext_vector_type(8))) short bf16x8;
typedef __attribute__((ext_vector_type(4))) float f32x4;
typedef __attribute__((ext_vector_type(2))) float f32x2;

__device__ __forceinline__ float bf2f(unsigned short u) {
    union { unsigned int i; float f; } x; x.i = ((unsigned int)u) << 16; return x.f;
}
__device__ __forceinline__ unsigned short f2bf(float f) {
    union { float f; unsigned int i; } x; x.f = f;
    unsigned int r = x.i + 0x7fffu + ((x.i >> 16) & 1u);
    return (unsigned short)(r >> 16);
}
__device__ __forceinline__ void unpack8(uint4 p, float* f) {
    f[0] = bf2f((unsigned short)(p.x & 0xffff)); f[1] = bf2f((unsigned short)(p.x >> 16));
    f[2] = bf2f((unsigned short)(p.y & 0xffff)); f[3] = bf2f((unsigned short)(p.y >> 16));
    f[4] = bf2f((unsigned short)(p.z & 0xffff)); f[5] = bf2f((unsigned short)(p.z >> 16));
    f[6] = bf2f((unsigned short)(p.w & 0xffff)); f[7] = bf2f((unsigned short)(p.w >> 16));
}
__device__ __forceinline__ void unpack8f8_w(unsigned int a, unsigned int b, float* f) {
    f32x2 t;
    t = __builtin_amdgcn_cvt_pk_f32_fp8((int)a, false); f[0] = t.x; f[1] = t.y;
    t = __builtin_amdgcn_cvt_pk_f32_fp8((int)a, true);  f[2] = t.x; f[3] = t.y;
    t = __builtin_amdgcn_cvt_pk_f32_fp8((int)b, false); f[4] = t.x; f[5] = t.y;
    t = __builtin_amdgcn_cvt_pk_f32_fp8((int)b, true);  f[6] = t.x; f[7] = t.y;
}
__device__ __forceinline__ unsigned char f2fp8(float v) {
    int pk = __builtin_amdgcn_cvt_pk_fp8_f32(v, v, 0, false);
    return (unsigned char)(pk & 0xff);
}
__device__ __forceinline__ void gld_lds16(const unsigned short* g, unsigned short* l) {
    __builtin_amdgcn_global_load_lds((const __attribute__((address_space(1))) void*)g,
                                     (__attribute__((address_space(3))) void*)l, 16, 0, 0);
}
__device__ __forceinline__ void gld_lds16b(const unsigned char* g, unsigned char* l) {
    __builtin_amdgcn_global_load_lds((const __attribute__((address_space(1))) void*)g,
                                     (__attribute__((address_space(3))) void*)l, 16, 0, 0);
}

// ---------------- convert: weights f32 W[K,N] -> bf16 WT[N,K] arena; also zeroes cursor ----------------
__global__ void convert_kernel(
    const float* __restrict__ lin_w,
    const float* __restrict__ qw0, const float* __restrict__ kw0,
    const float* __restrict__ vw0, const float* __restrict__ sw0,
    const float* __restrict__ qw1, const float* __restrict__ kw1,
    const float* __restrict__ vw1, const float* __restrict__ sw1,
    unsigned short* __restrict__ arena, int* __restrict__ cursor)
{
    int idx = blockIdx.x * 256 + threadIdx.x;
    if (idx < NNODE) cursor[idx] = 0;
    int id2 = idx - NNODE;
    if (id2 < 0 || id2 >= 458752) return;
    float v;
    if (id2 < 32768) {
        int n = id2 >> 8, k = id2 & 255;
        v = lin_w[k * 128 + n];
    } else {
        int t = id2 - 32768;
        int l = t / 212992, r = t % 212992;
        int n = r >> 7, k = r & 127;
        const float* qw = l ? qw1 : qw0;
        const float* kw = l ? kw1 : kw0;
        const float* vw = l ? vw1 : vw0;
        const float* sw = l ? sw1 : sw0;
        if (n < 1536) {
            const float* w = (n < 512) ? qw : (n < 1024) ? kw : vw;
            v = w[k * 512 + (n & 511)];
        } else {
            v = sw[k * 128 + (n - 1536)];
        }
    }
    arena[id2] = f2bf(v);
}

// ---------------- GEMM0: input projection. A = x f32 (convert in staging regs), K=256, N=128 ----------------
__global__ __launch_bounds__(256) void mfma_gemm0(
    const float* __restrict__ A, const unsigned short* __restrict__ WT,
    const float* __restrict__ b0, unsigned short* __restrict__ hbf_out)
{
    __shared__ unsigned short smem[8192];
    unsigned short* As = smem;
    unsigned short* Bs = smem + 4096;
    unsigned short* ot = smem;
    const int K = 256;

    int tid = threadIdx.x;
    int lane = tid & 63;
    int w = tid >> 6;
    int wm = w & 1, wn = w >> 1;
    int bm = blockIdx.x * 128;

    // A staging (register convert): thread covers rows r0 and r0+64, 8 cols at c0
    int r0 = tid >> 2;
    int c0 = (tid & 3) * 8;
    int g0 = bm + r0;      if (g0 > NNODE - 1) g0 = NNODE - 1;
    int g1 = bm + r0 + 64; if (g1 > NNODE - 1) g1 = NNODE - 1;
    // WT staging (async DMA)
    int srow = lane >> 2;
    int scol = (lane & 3) * 8;
    int br0 = w * 32 + srow;
    int br1 = w * 32 + 16 + srow;

    f32x4 acc[4][4] = {};
    int arow = wm * 64 + (lane & 15);
    int brow = wn * 64 + (lane & 15);
    int koff = (lane >> 4) * 8;

    for (int k0 = 0; k0 < K; k0 += 32) {
        {
            const float4* p0 = (const float4*)(A + (size_t)g0 * K + k0 + c0);
            float4 u = p0[0], v = p0[1];
            unsigned short t0[8] = {f2bf(u.x), f2bf(u.y), f2bf(u.z), f2bf(u.w),
                                    f2bf(v.x), f2bf(v.y), f2bf(v.z), f2bf(v.w)};
            *(uint4*)&As[r0 * 32 + c0] = *(uint4*)t0;
            const float4* p1 = (const float4*)(A + (size_t)g1 * K + k0 + c0);
            u = p1[0]; v = p1[1];
            unsigned short t1[8] = {f2bf(u.x), f2bf(u.y), f2bf(u.z), f2bf(u.w),
                                    f2bf(v.x), f2bf(v.y), f2bf(v.z), f2bf(v.w)};
            *(uint4*)&As[(r0 + 64) * 32 + c0] = *(uint4*)t1;
        }
        gld_lds16(WT + (size_t)br0 * K + k0 + scol, Bs + (w * 32) * 32);
        gld_lds16(WT + (size_t)br1 * K + k0 + scol, Bs + (w * 32 + 16) * 32);
        __syncthreads();
        bf16x8 fa[4], fb[4];
#pragma unroll
        for (int i = 0; i < 4; i++) fa[i] = *(const bf16x8*)&As[(arow + i * 16) * 32 + koff];
#pragma unroll
        for (int i = 0; i < 4; i++) fb[i] = *(const bf16x8*)&Bs[(brow + i * 16) * 32 + koff];
#pragma unroll
        for (int mi = 0; mi < 4; mi++)
#pragma unroll
            for (int ni = 0; ni < 4; ni++)
                acc[mi][ni] = __builtin_amdgcn_mfma_f32_16x16x32_bf16(fa[mi], fb[ni], acc[mi][ni], 0, 0, 0);
        __syncthreads();
    }

    int quad = lane >> 4, lcol = lane & 15;
#pragma unroll
    for (int hh = 0; hh < 2; hh++) {
        __syncthreads();
        if (wm == hh) {
#pragma unroll
            for (int mi = 0; mi < 4; mi++) {
#pragma unroll
                for (int ni = 0; ni < 4; ni++) {
                    int lc = wn * 64 + ni * 16 + lcol;
                    float bias = b0[lc];
#pragma unroll
                    for (int reg = 0; reg < 4; reg++) {
                        float v = fmaxf(acc[mi][ni][reg] + bias, 0.f);
                        ot[(mi * 16 + quad * 4 + reg) * 128 + lc] = f2bf(v);
                    }
                }
            }
        }
        __syncthreads();
        int r = tid >> 2, ch = tid & 3;
        int row = bm + hh * 64 + r;
        if (row < NNODE) {
            uint4* dp = (uint4*)(hbf_out + (size_t)row * HIDV + ch * 32);
            const uint4* sp = (const uint4*)(ot + r * 128 + ch * 32);
#pragma unroll
            for (int q = 0; q < 4; q++) dp[q] = sp[q];
        }
    }
}

// ---------------- GEMM1: panel-looped, A resident in LDS (r13 epilogues) ----------------
// grid (157, 2): y=0 -> panels 0..6, y=1 -> panels 7..12.
// panel p (bn=p*128): p<4 -> qb bf16; 4<=p<12 -> kv8 fp8; p==12 -> pre16 bf16.
__global__ __launch_bounds__(256) void mfma_gemm1(
    const unsigned short* __restrict__ A, const unsigned short* __restrict__ WT,
    const float* __restrict__ b0, const float* __restrict__ b1,
    const float* __restrict__ b2, const float* __restrict__ b3,
    unsigned short* __restrict__ qb_out, unsigned char* __restrict__ kv8_out,
    unsigned short* __restrict__ pre16_out)
{
    __shared__ unsigned short As[16384];   // 32 KB A tile, 4 k-chunks x [128][32]
    __shared__ unsigned short Ws[16384];   // 32 KB WT panel; reused as epilogue tile
    unsigned short* ot = Ws;
    unsigned char* ot8 = (unsigned char*)Ws;
    const int K = 128;

    int tid = threadIdx.x;
    int lane = tid & 63;
    int w = tid >> 6;
    int wm = w & 1, wn = w >> 1;
    int bm = blockIdx.x * 128;
    int p0 = (blockIdx.y == 0) ? 0 : 7;
    int p1 = (blockIdx.y == 0) ? 7 : 13;

    int srow = lane >> 2;
    int scol = (lane & 3) * 8;
    int sr0 = w * 32 + srow;
    int sr1 = w * 32 + 16 + srow;
    int ar0 = bm + sr0; if (ar0 > NNODE - 1) ar0 = NNODE - 1;
    int ar1 = bm + sr1; if (ar1 > NNODE - 1) ar1 = NNODE - 1;

    // stage A once
#pragma unroll
    for (int c = 0; c < 4; c++) {
        int k0 = c * 32;
        gld_lds16(A + (size_t)ar0 * K + k0 + scol, As + c * 4096 + sr0 * 32);
        gld_lds16(A + (size_t)ar1 * K + k0 + scol, As + c * 4096 + sr1 * 32);
    }

    int arow = wm * 64 + (lane & 15);
    int brow = wn * 64 + (lane & 15);
    int koff = (lane >> 4) * 8;
    int quad = lane >> 4, lcol = lane & 15;

    for (int p = p0; p < p1; p++) {
        int bn = p * 128;
        // stage WT panel
#pragma unroll
        for (int c = 0; c < 4; c++) {
            int k0 = c * 32;
            gld_lds16(WT + (size_t)(bn + sr0) * K + k0 + scol, Ws + c * 4096 + sr0 * 32);
            gld_lds16(WT + (size_t)(bn + sr1) * K + k0 + scol, Ws + c * 4096 + sr1 * 32);
        }
        __syncthreads();   // drains all DMA (incl. A on first iter)

        f32x4 acc[4][4] = {};
#pragma unroll
        for (int c = 0; c < 4; c++) {
            bf16x8 fa[4], fb[4];
#pragma unroll
            for (int i = 0; i < 4; i++) fa[i] = *(const bf16x8*)&As[c * 4096 + (arow + i * 16) * 32 + koff];
#pragma unroll
            for (int i = 0; i < 4; i++) fb[i] = *(const bf16x8*)&Ws[c * 4096 + (brow + i * 16) * 32 + koff];
#pragma unroll
            for (int mi = 0; mi < 4; mi++)
#pragma unroll
                for (int ni = 0; ni < 4; ni++)
                    acc[mi][ni] = __builtin_amdgcn_mfma_f32_16x16x32_bf16(fa[mi], fb[ni], acc[mi][ni], 0, 0, 0);
        }
        __syncthreads();   // Ws dead; safe to reuse as ot

        if (p < 4 || p == 12) {
            // bf16 output: full 128x128 tile staged in ot (rows are 128 shorts = 256 B)
            const float* bb = (p < 4) ? (b0 + bn) : b3;
#pragma unroll
            for (int mi = 0; mi < 4; mi++) {
#pragma unroll
                for (int ni = 0; ni < 4; ni++) {
                    int lc = wn * 64 + ni * 16 + lcol;
                    float bias = bb[lc];
#pragma unroll
                    for (int reg = 0; reg < 4; reg++)
                        ot[(wm * 64 + mi * 16 + quad * 4 + reg) * 128 + lc] = f2bf(acc[mi][ni][reg] + bias);
                }
            }
            __syncthreads();
            // 2 threads/row, each stores 64 shorts = 128 B = 8 uint4
            int r = tid >> 1, hf = tid & 1;
            int row = bm + r;
            if (row < NNODE) {
                unsigned short* dst = (p < 4) ? (qb_out + (size_t)row * 512 + bn + hf * 64)
                                              : (pre16_out + (size_t)row * HIDV + hf * 64);
                const uint4* sp = (const uint4*)(ot + r * 128 + hf * 64);
                uint4* dp = (uint4*)dst;
#pragma unroll
                for (int q = 0; q < 8; q++) dp[q] = sp[q];
            }
            __syncthreads();
        } else {
            // fp8 output (K/V): full 128x128 byte tile (rows are 128 B)
            const float* bb = (bn < 1024) ? (b1 + bn - 512) : (b2 + bn - 1024);
            int coff = bn - 512;
#pragma unroll
            for (int mi = 0; mi < 4; mi++) {
#pragma unroll
                for (int ni = 0; ni < 4; ni++) {
                    int lc = wn * 64 + ni * 16 + lcol;
                    float bias = bb[lc];
#pragma unroll
                    for (int reg = 0; reg < 4; reg++)
                        ot8[(wm * 64 + mi * 16 + quad * 4 + reg) * 128 + lc] = f2fp8(acc[mi][ni][reg] + bias);
                }
            }
            __syncthreads();
            int r = tid >> 1, hf = tid & 1;
            int row = bm + r;
            if (row < NNODE) {
                uint4* dp = (uint4*)(kv8_out + (size_t)row * 1024 + coff + hf * 64);
                const uint4* sp = (const uint4*)(ot8 + r * 128 + hf * 64);
#pragma unroll
                for (int q = 0; q < 4; q++) dp[q] = sp[q];
            }
            __syncthreads();
        }
    }
}

// ---------------- bucket scatter ----------------
__global__ void scatter_kernel(const int* __restrict__ ei, int* __restrict__ cursor,
                               int* __restrict__ bucket) {
    int e = blockIdx.x * blockDim.x + threadIdx.x;
    if (e < NEDGE) {
        int d = ei[NEDGE + e];
        int slot = atomicAdd(&cursor[d], 1);
        if (slot < DEGCAP) bucket[d * DEGCAP + slot] = ei[e];
    }
}

// ---------------- Fused attention + residual + LayerNorm (r13 version) ----------------
__global__ __launch_bounds__(256) void attn_ln_kernel(
    const unsigned short* __restrict__ qb, const unsigned char* __restrict__ kv8,
    const int* __restrict__ cursor, const int* __restrict__ bucket,
    const unsigned short* __restrict__ pre16, const float* __restrict__ g,
    const float* __restrict__ b,
    unsigned short* __restrict__ hbf /* in: residual; out: LN result */,
    float* __restrict__ extout)
{
    __shared__ __align__(16) unsigned char ring[4][2][BAT * 1024]; // 32 KB
    int lane = threadIdx.x & 63;
    int wid = threadIdx.x >> 6;
    int i = blockIdx.x * 4 + wid;
    int cnt = cursor[i]; if (cnt > DEGCAP) cnt = DEGCAP;
    const int* bk = bucket + i * DEGCAP;

    int hg = lane >> 4;
    int sl = lane & 15;

    float qr[8];
    {
        uint4 p = *(const uint4*)(qb + (size_t)i * 512 + lane * 8);
        unpack8(p, qr);
#pragma unroll
        for (int j = 0; j < 8; j++) qr[j] *= 0.0883883476483184f; // 1/sqrt(128)
    }

    float m = -INFINITY, l = 0.f;
    float acc[8] = {0.f, 0.f, 0.f, 0.f, 0.f, 0.f, 0.f, 0.f};

    if (cnt > 0) {
        int myidx = bk[(lane < cnt) ? lane : 0];

        auto issue = [&](int bb, unsigned char* half) {
#pragma unroll
            for (int t = 0; t < BAT; t++) {
                int j = bb * BAT + t; if (j >= cnt) j = cnt - 1;
                int src = __shfl(myidx, j);
                gld_lds16b(kv8 + (size_t)src * 1024 + lane * 16, half + t * 1024);
            }
        };

        issue(0, ring[wid][0]);
        for (int bb = 0; bb * BAT < cnt; bb++) {
            unsigned char* cur = ring[wid][bb & 1];
            unsigned char* nxt = ring[wid][(bb + 1) & 1];
            bool more = (bb + 1) * BAT < cnt;
            if (more) {
                asm volatile("s_waitcnt lgkmcnt(0)" ::: "memory");
                issue(bb + 1, nxt);
                asm volatile("s_waitcnt vmcnt(4)" ::: "memory");
            } else {
                asm volatile("s_waitcnt vmcnt(0)" ::: "memory");
            }
            int rem = cnt - bb * BAT;

            float d[BAT];
#pragma unroll
            for (int t = 0; t < BAT; t++) d[t] = -3.0e38f;
#pragma unroll
            for (int t = 0; t < BAT; t++) {
                if (t >= rem) break;
                uint2 kk = *(const uint2*)(cur + t * 1024 + hg * 128 + sl * 8);
                float kf[8];
                unpack8f8_w(kk.x, kk.y, kf);
                d[t] = qr[0] * kf[0] + qr[1] * kf[1] + qr[2] * kf[2] + qr[3] * kf[3] +
                       qr[4] * kf[4] + qr[5] * kf[5] + qr[6] * kf[6] + qr[7] * kf[7];
            }
#pragma unroll
            for (int t = 0; t < BAT; t++) { if (t >= rem) break; d[t] += __shfl_xor(d[t], 8); }
#pragma unroll
            for (int t = 0; t < BAT; t++) { if (t >= rem) break; d[t] += __shfl_xor(d[t], 4); }
#pragma unroll
            for (int t = 0; t < BAT; t++) { if (t >= rem) break; d[t] += __shfl_xor(d[t], 2); }
#pragma unroll
            for (int t = 0; t < BAT; t++) { if (t >= rem) break; d[t] += __shfl_xor(d[t], 1); }

            float mq = d[0];
#pragma unroll
            for (int t = 1; t < BAT; t++) mq = fmaxf(mq, d[t]);
            float mn = fmaxf(m, mq);
            float scale = __expf(m - mn);
            float p[BAT];
            float psum = 0.f;
#pragma unroll
            for (int t = 0; t < BAT; t++) { p[t] = __expf(d[t] - mn); psum += p[t]; }
            l = l * scale + psum;
            m = mn;
#pragma unroll
            for (int c = 0; c < 8; c++) acc[c] *= scale;
#pragma unroll
            for (int t = 0; t < BAT; t++) {
                if (t >= rem) break;
                uint2 vv = *(const uint2*)(cur + t * 1024 + 512 + hg * 128 + sl * 8);
                float vf[8];
                unpack8f8_w(vv.x, vv.y, vf);
                float pt = p[t];
#pragma unroll
                for (int c = 0; c < 8; c++) acc[c] += pt * vf[c];
            }
        }
    }

    float linv = 0.25f / (l + 1e-16f);
#pragma unroll
    for (int c = 0; c < 8; c++) acc[c] *= linv;
#pragma unroll
    for (int c = 0; c < 8; c++) {
        acc[c] += __shfl_xor(acc[c], 16);
        acc[c] += __shfl_xor(acc[c], 32);
    }

    size_t base = (size_t)i * HIDV + sl * 8;
    float pv[8], hv[8];
    unpack8(*(const uint4*)(pre16 + base), pv);
    unpack8(*(const uint4*)(hbf + base), hv);
    float vals[8];
#pragma unroll
    for (int c = 0; c < 8; c++) vals[c] = acc[c] + pv[c] + hv[c];

    float s = 0.f;
#pragma unroll
    for (int c = 0; c < 8; c++) s += vals[c];
    s += __shfl_xor(s, 1); s += __shfl_xor(s, 2);
    s += __shfl_xor(s, 4); s += __shfl_xor(s, 8);
    float mu = s * (1.f / 128.f);
    float vs = 0.f;
#pragma unroll
    for (int c = 0; c < 8; c++) { float dx = vals[c] - mu; vs += dx * dx; }
    vs += __shfl_xor(vs, 1); vs += __shfl_xor(vs, 2);
    vs += __shfl_xor(vs, 4); vs += __shfl_xor(vs, 8);
    float rstd = rsqrtf(vs * (1.f / 128.f) + 1e-5f);

    float4 g0 = ((const float4*)(g + sl * 8))[0];
    float4 g1 = ((const float4*)(g + sl * 8))[1];
    float4 bb0 = ((const float4*)(b + sl * 8))[0];
    float4 bb1 = ((const float4*)(b + sl * 8))[1];
    float y[8];
    y[0] = (vals[0] - mu) * rstd * g0.x + bb0.x; y[1] = (vals[1] - mu) * rstd * g0.y + bb0.y;
    y[2] = (vals[2] - mu) * rstd * g0.z + bb0.z; y[3] = (vals[3] - mu) * rstd * g0.w + bb0.w;
    y[4] = (vals[4] - mu) * rstd * g1.x + bb1.x; y[5] = (vals[5] - mu) * rstd * g1.y + bb1.y;
    y[6] = (vals[6] - mu) * rstd * g1.z + bb1.z; y[7] = (vals[7] - mu) * rstd * g1.w + bb1.w;

    if (lane < 16) {
        unsigned short tmp[8] = {f2bf(y[0]), f2bf(y[1]), f2bf(y[2]), f2bf(y[3]),
                                 f2bf(y[4]), f2bf(y[5]), f2bf(y[6]), f2bf(y[7])};
        *(uint4*)(hbf + base) = *(uint4*)tmp;
        if (extout) {
            ((float4*)(extout + base))[0] = make_float4(y[0], y[1], y[2], y[3]);
            ((float4*)(extout + base))[1] = make_float4(y[4], y[5], y[6], y[7]);
        }
    }
}

extern "C" void kernel_launch(void* const* d_in, const int* in_sizes, int n_in,
                              void* d_out, int out_size, void* d_ws, size_t ws_size,
                              hipStream_t stream) {
    const float* x = (const float*)d_in[0];
    const int* ei = (const int*)d_in[1];

    char* ws = (char*)d_ws;
    unsigned short* hbf = (unsigned short*)(ws + 0);          // 5.12 MB
    unsigned short* pre16 = (unsigned short*)(ws + 5120000);  // 5.12 MB
    unsigned short* qb = (unsigned short*)(ws + 10240000);    // 20.48 MB (N x 512 bf16)
    unsigned char* kv8 = (unsigned char*)(ws + 30720000);     // 20.48 MB (N x 1024 fp8)
    int* cursor = (int*)(ws + 51200000);                      // 80 KB
    int* bucket = (int*)(ws + 51280000);                      // N x 64 ints = 5.12 MB
    unsigned short* arena = (unsigned short*)(ws + 56400000); // 0.92 MB

    // weights conversion + cursor zero (one launch)
    convert_kernel<<<(NNODE + 458752 + 255) / 256, 256, 0, stream>>>(
        (const float*)d_in[2],
        (const float*)d_in[4], (const float*)d_in[6], (const float*)d_in[8], (const float*)d_in[10],
        (const float*)d_in[14], (const float*)d_in[16], (const float*)d_in[18], (const float*)d_in[20],
        arena, cursor);

    scatter_kernel<<<(NEDGE + 255) / 256, 256, 0, stream>>>(ei, cursor, bucket);

    const int GM = (NNODE + 127) / 128; // 157

    mfma_gemm0<<<GM, 256, 0, stream>>>(x, arena, (const float*)d_in[3], hbf);

    for (int l = 0; l < 2; l++) {
        int o = 4 + l * 10;
        const unsigned short* WT = arena + 32768 + l * 212992;
        mfma_gemm1<<<dim3(GM, 2), 256, 0, stream>>>(
            hbf, WT,
            (const float*)d_in[o + 1], (const float*)d_in[o + 3],
            (const float*)d_in[o + 5], (const float*)d_in[o + 7],
            qb, kv8, pre16);

        attn_ln_kernel<<<NNODE / 4, 256, 0, stream>>>(
            qb, kv8, cursor, bucket, pre16,
            (const float*)d_in[o + 8], (const float*)d_in[o + 9],
            hbf, (l == 1) ? (float*)d_out : nullptr);
    }
}